// Round 17
// baseline (161.433 us; speedup 1.0000x reference)
//
#include <hip/hip_runtime.h>
#include <hip/hip_bf16.h>
#include <stdint.h>

// RecNN: B=2048, L=256, F=64, H=128. One WG (512 thr, 8 waves) per 4 batch
// elems; grid 512 = TWO blocks per CU (80 KB LDS each = exactly 160 KiB).
// Round-17: amdgpu_waves_per_eu(2, 4) — semantics pinned by R15/R16:
//   min drives the allocator budget (256/min: (2,*)->128-reg cap, no spill;
//   (4,4) gave 64 and spilled), max caps RUNTIME waves/SIMD ((2,2) blocked
//   the 2nd block -> 22% occupancy; (4,4) reached 45%).
// (2,4) = R16's spill-free codegen + R15's 2-blocks-per-CU residency: the
// two blocks' barrier-drain idle (~25-30% of R11's runtime) interleaves.
// Each wave owns ONE 16-col output tile (56 weight VGPRs — the only no-spill
// footprint; R2/3/5/7/12/13 all failed to exceed it). swz256 XOR is
// (row&15)<<4 so the 4-rows/node ldA_nl read set is 2-way (free) not 4-way.

#define B_TOT 2048
#define LL    256
#define FF    64
#define HH    128
#define LF    (LL*FF)
#define BC    4
#define NTHR  512
#define NSUB  16

typedef __bf16 v8bf __attribute__((ext_vector_type(8)));
typedef float  v4f  __attribute__((ext_vector_type(4)));

// ---- LDS layout (bytes) — 81920 total (2 blocks/CU x 80 KB = 160 KB) ----
#define XB_OFF    0        // [64]x128B bf16 swz128: leaf x               8192
#define XB2_OFF   8192     // [64]x128B bf16 swz128: data1..4 + root      8192
#define DB_OFF    16384    // [32]x256B f32 swz256: data1 / data3         8192
#define DB2_OFF   24576    // [20]x256B: rows0-15 data2 f32 then U2 bf16;
                           //            rows16-19 data4 f32              5120
#define HA_OFF    29696    // [64]x256B bf16 swz256: h0 / h2             16384
#define HB_OFF    46080    // [32]x256B bf16: h1 / h3 / z2                8192
#define U_OFF     54272    // [32]x256B bf16: u1 / u3@0 / u4@16 / z1      8192
#define HCA_OFF   62464    // [16]x256B bf16: root h (buffer A)           4096
#define HCB_OFF   66560    // [16]x256B bf16: root h (buffer B)           4096
#define DCUR_OFF  70656    // [4]x256B f32: root data                     1024
#define HSTK_OFF  71680    // 4 x 1024 (4 real rows each)                 4096
#define DSTK_OFF  75776    // 4 x 1024                                    4096
#define BIAS_OFF  79872    // 4 x 512B f32                                2048
#define LDS_BYTES 81920

// XOR (row&15)<<4: 16 rows with distinct row&15 -> 2-way max (free).
// Bijective within each 256B row.
__device__ __forceinline__ uint32_t swz256(uint32_t row, uint32_t b){
    return (row*256u + b) ^ ((row & 15u) << 4);
}
__device__ __forceinline__ uint32_t swz128(uint32_t row, uint32_t b){
    return (row*128u + b) ^ ((row & 7u) << 4);
}
__device__ __forceinline__ v4f mfma16(v8bf a, v8bf b, v4f c){
    return __builtin_amdgcn_mfma_f32_16x16x32_bf16(a, b, c, 0, 0, 0);
}
__device__ __forceinline__ uint32_t pk2(float a, float b){
    uint32_t lo = (uint32_t)__builtin_bit_cast(unsigned short, (__bf16)a);
    uint32_t hi = (uint32_t)__builtin_bit_cast(unsigned short, (__bf16)b);
    return lo | (hi << 16);
}
__device__ __forceinline__ uint2 pk4(v4f v){
    return make_uint2(pk2(v[0], v[1]), pk2(v[2], v[3]));
}

// B-fragment: lane holds col n0+(l&15), k = k0 + 8*(l>>4) + j. W row-major [K][128] f32.
__device__ __forceinline__ v8bf ldW(const float* __restrict__ W, int k0, int n0){
    uint32_t lane = threadIdx.x & 63u;
    int n = n0 + (int)(lane & 15u);
    int k = k0 + (int)((lane >> 4) << 3);
    v8bf r;
    #pragma unroll
    for (int j = 0; j < 8; ++j) r[j] = (__bf16)W[(k + j)*HH + n];
    return r;
}

// A-frag from bf16 64-col panel (swz128). rows >= realrows -> 0.
__device__ __forceinline__ v8bf ldX(const char* xb, uint32_t row0, uint32_t mt,
                                    uint32_t kf, uint32_t realrows){
    uint32_t lane = threadIdx.x & 63u;
    uint32_t rl = mt*16u + (lane & 15u);
    if (rl >= realrows){
        v8bf z;
        #pragma unroll
        for (int j = 0; j < 8; ++j) z[j] = (__bf16)0.0f;
        return z;
    }
    return *reinterpret_cast<const v8bf*>(xb + swz128(row0 + rl, kf*64u + ((lane>>4)<<4)));
}

// A-frag from 16-row bf16 buffer (swz256), row = lane&15 (merge/head GEMMs)
__device__ __forceinline__ v8bf ldH(const char* buf, uint32_t kf){
    uint32_t lane = threadIdx.x & 63u;
    return *reinterpret_cast<const v8bf*>(buf + swz256(lane & 15u,
                                          kf*64u + ((lane>>4)<<4)));
}

// A-frag for subtree nl GEMM (node-major, 4 rows/node): out tile mt covers
// out nodes 4mt..4mt+3; out row r -> node 4mt+(r>>2), b=r&3; children rows
// 32mt + 8*(r>>2) + sec*4 + (r&3) (sec 0/1 = left/right); u row 16mt+r.
__device__ __forceinline__ v8bf ldA_nl(const char* hprev, const char* ub,
                                       uint32_t mt, uint32_t kf){
    uint32_t lane = threadIdx.x & 63u, r = lane & 15u;
    uint32_t kb = (kf & 3u)*64u + ((lane >> 4) << 4);
    uint32_t sec = kf >> 2;
    if (sec < 2u){
        uint32_t row = mt*32u + ((r >> 2) << 3) + sec*4u + (r & 3u);
        return *reinterpret_cast<const v8bf*>(hprev + swz256(row, kb));
    }
    return *reinterpret_cast<const v8bf*>(ub + swz256(mt*16u + r, kb));
}

// Epilogue: relu(acc+bias) -> bf16 swz256 LDS, rows row0+(l>>4)*4+r, col 16nt+(l&15)
__device__ __forceinline__ void epi(char* dst, uint32_t row0, v4f acc, int nt,
                                    const float* bias){
    uint32_t lane = threadIdx.x & 63u;
    uint32_t col = (uint32_t)nt*16u + (lane & 15u);
    float bv = bias[col];
    uint32_t r0 = row0 + ((lane >> 4) << 2);
    #pragma unroll
    for (int r = 0; r < 4; ++r){
        float v = fmaxf(acc[r] + bv, 0.f);
        *reinterpret_cast<__bf16*>(dst + swz256(r0 + r, col*2u)) = (__bf16)v;
    }
}

// data/leaf GEMM: relu(A @ Wleaf + b), A from bf16 panel, 1 nt per wave
template<int MTN>
__device__ __forceinline__ void gemm_x(const char* xb, uint32_t row0, uint32_t realrows,
                                       char* dst, uint32_t mtB, const v8bf (&wlf)[2],
                                       int nt, const float* bias){
    v4f acc[MTN];
    #pragma unroll
    for (int i = 0; i < MTN; ++i) acc[i] = (v4f){0,0,0,0};
    #pragma unroll
    for (uint32_t kf = 0; kf < 2; ++kf){
        v8bf a[MTN];
        #pragma unroll
        for (int i = 0; i < MTN; ++i) a[i] = ldX(xb, row0, mtB + i, kf, realrows);
        #pragma unroll
        for (int i = 0; i < MTN; ++i) acc[i] = mfma16(a[i], wlf[kf], acc[i]);
    }
    #pragma unroll
    for (int i = 0; i < MTN; ++i) epi(dst, (mtB + i)*16u, acc[i], nt, bias);
}

// nl GEMM: relu([h_even|h_odd|u] @ Wnl + b), node-major, 1 nt per wave
template<int MTN>
__device__ __forceinline__ void gemm_nl(const char* hprev, const char* ub, char* dst,
                                        uint32_t mtB, const v8bf (&wnl)[12],
                                        int nt, const float* bias){
    v4f acc[MTN];
    #pragma unroll
    for (int i = 0; i < MTN; ++i) acc[i] = (v4f){0,0,0,0};
    #pragma unroll
    for (uint32_t kf = 0; kf < 12; ++kf){
        v8bf a[MTN];
        #pragma unroll
        for (int i = 0; i < MTN; ++i) a[i] = ldA_nl(hprev, ub, mtB + i, kf);
        #pragma unroll
        for (int i = 0; i < MTN; ++i) acc[i] = mfma16(a[i], wnl[kf], acc[i]);
    }
    #pragma unroll
    for (int i = 0; i < MTN; ++i) epi(dst, (mtB + i)*16u, acc[i], nt, bias);
}

__global__ __launch_bounds__(NTHR)
__attribute__((amdgpu_waves_per_eu(2, 4)))
void recnn_kernel(const float* __restrict__ Xg,
                  const float* __restrict__ Wleaf, const float* __restrict__ bleaf,
                  const float* __restrict__ Wnl,   const float* __restrict__ bnl,
                  const float* __restrict__ W1g,   const float* __restrict__ b1g,
                  const float* __restrict__ W2g,   const float* __restrict__ b2g,
                  const float* __restrict__ W3g,   const float* __restrict__ b3g,
                  float* __restrict__ Yg)
{
    __shared__ __align__(16) char lds[LDS_BYTES];
    const int t    = threadIdx.x;
    const int wave = t >> 6;
    const int base = blockIdx.x * BC;

    char*  XB   = lds + XB_OFF;
    char*  XB2  = lds + XB2_OFF;
    char*  DB   = lds + DB_OFF;
    char*  DB2  = lds + DB2_OFF;
    char*  U2   = lds + DB2_OFF;           // rows 0-15, bf16 (data2-f32 dead by then)
    char*  HA   = lds + HA_OFF;
    char*  HB   = lds + HB_OFF;
    char*  Ub   = lds + U_OFF;
    char*  DCUR = lds + DCUR_OFF;
    char*  HSTK = lds + HSTK_OFF;
    char*  DSTK = lds + DSTK_OFF;
    float* BL   = (float*)(lds + BIAS_OFF);
    float* BN   = BL + 128;
    float* B1L  = BL + 256;
    float* B2L  = BL + 384;

    char* hc_cur = lds + HCA_OFF;
    char* hc_alt = lds + HCB_OFF;

    if (t < 128){
        BL[t]  = bleaf[t];
        BN[t]  = bnl[t];
        B1L[t] = b1g[t];
        B2L[t] = b2g[t];
    }

    // Persistent weights: wave owns output cols [16*wave, 16*wave+16) — 56 VGPRs
    const int nt = wave;
    const int n0 = wave << 4;
    v8bf wlf[2], wnl[12];
    #pragma unroll
    for (int kf = 0; kf < 2; ++kf)  wlf[kf] = ldW(Wleaf, kf*32, n0);
    #pragma unroll
    for (int kf = 0; kf < 12; ++kf) wnl[kf] = ldW(Wnl, kf*32, n0);

    // fused pairwise sum (node-major, 4 rows/node): src rows n*8+b, n*8+4+b
    // -> dst row n*4+b (f32) + XB2 bf16 mirror
    auto sum_level = [&](char* dstF, uint32_t dRow0, uint32_t xRow0,
                         const char* srcF, uint32_t sRow0, int outrows){
        int total = outrows * 16;
        for (int idx = t; idx < total; idx += NTHR){
            uint32_t row = (uint32_t)(idx >> 4), q = (uint32_t)(idx & 15);
            uint32_t n = row >> 2, b = row & 3u;
            v4f a = *reinterpret_cast<const v4f*>(srcF + swz256(sRow0 + n*8u + b,      q*16u));
            v4f c = *reinterpret_cast<const v4f*>(srcF + swz256(sRow0 + n*8u + 4u + b, q*16u));
            v4f sv = a + c;
            *reinterpret_cast<v4f*>(dstF + swz256(dRow0 + row, q*16u)) = sv;
            *reinterpret_cast<uint2*>(XB2 + swz128(xRow0 + row, q*8u)) = pk4(sv);
        }
    };

    int sp = 0;
    for (int s = 0; s < NSUB; ++s){
        // push previous root (4 real rows = 1024B each)
        if (s > 0){
            if (t < 256){
                ((uint32_t*)(HSTK + sp*1024))[t] = ((const uint32_t*)hc_cur)[t];
                ((uint32_t*)(DSTK + sp*1024))[t] = ((const uint32_t*)DCUR)[t];
            }
            ++sp;
        }
        // stage: x -> XB bf16; data1 -> DB f32 + XB2[0:32) bf16
        {
            uint32_t q = (uint32_t)(t & 15), rp = (uint32_t)(t >> 4);
            uint32_t n = rp >> 2, b = rp & 3u;
            const float* gp = Xg + (size_t)(base + b)*LF + (size_t)(s*16 + 2*n)*FF + q*4;
            v4f xA = *reinterpret_cast<const v4f*>(gp);
            v4f xC = *reinterpret_cast<const v4f*>(gp + FF);
            uint32_t rowA = n*8u + b;              // leaf 2n ; leaf 2n+1 = rowA+4
            *reinterpret_cast<uint2*>(XB + swz128(rowA,      q*8u)) = pk4(xA);
            *reinterpret_cast<uint2*>(XB + swz128(rowA + 4u, q*8u)) = pk4(xC);
            v4f sv = xA + xC;
            *reinterpret_cast<v4f*>(DB + swz256(rp, q*16u)) = sv;
            *reinterpret_cast<uint2*>(XB2 + swz128(rp, q*8u)) = pk4(sv);
        }
        __syncthreads();

        // F1: leaf M=64 -> HA ; data2 = sum(data1) -> DB2[0:16)f32 + XB2[32:48)
        gemm_x<4>(XB, 0, 64, HA, 0, wlf, nt, BL);
        sum_level(DB2, 0, 32, DB, 0, 16);
        __syncthreads();

        // F2: u1 M=32 -> U ; data3 = sum(data2 f32) -> DB[0:8) + XB2[48:56)
        gemm_x<2>(XB2, 0, 32, Ub, 0, wlf, nt, BL);
        sum_level(DB, 0, 48, DB2, 0, 8);
        __syncthreads();

        // F3: nl1 M=32 -> HB ; u2 M=16 -> U2 (over dead data2 f32) ;
        //     data4 = sum(data3) -> DB2[16:20) + XB2[56:60)
        gemm_nl<2>(HA, Ub, HB, 0, wnl, nt, BN);
        gemm_x<1>(XB2, 32, 16, U2, 0, wlf, nt, BL);
        sum_level(DB2, 16, 56, DB, 0, 4);
        __syncthreads();

        // F4: nl2 M=16 -> HA[0:16) ; u3 M=8 -> U[0:16)
        gemm_nl<1>(HB, U2, HA, 0, wnl, nt, BN);
        gemm_x<1>(XB2, 48, 8, Ub, 0, wlf, nt, BL);
        __syncthreads();

        // F5: nl3 M=8 -> HB[0:16) ; u4 M=4 -> U[16:32)
        gemm_nl<1>(HA, Ub, HB, 0, wnl, nt, BN);
        gemm_x<1>(XB2, 56, 4, Ub + 16*256, 0, wlf, nt, BL);
        __syncthreads();

        // F6: nl4 M=4 -> hc_cur ; DCUR <- data4 f32
        gemm_nl<1>(HB, Ub + 16*256, hc_cur, 0, wnl, nt, BN);
        if (t < 256){
            uint32_t row = (uint32_t)(t >> 6), f = (uint32_t)(t & 63);
            *reinterpret_cast<float*>(DCUR + swz256(row, f*4u)) =
                *reinterpret_cast<const float*>(DB2 + swz256(16u + row, f*4u));
        }
        __syncthreads();

        // DFS merges among subtree roots (M=4 padded to 16), HCUR double-buffered
        int nm = __builtin_ctz(s + 1);
        for (int m = 0; m < nm; ++m){
            --sp;
            const char* hl = HSTK + sp*1024;
            if (t < 256){   // (a) root data sum + bf16 mirror -> XB2[60:64)
                uint32_t row = (uint32_t)(t >> 6), f = (uint32_t)(t & 63);
                float v = *reinterpret_cast<const float*>(DCUR + swz256(row, f*4u))
                        + *reinterpret_cast<const float*>(DSTK + sp*1024 + swz256(row, f*4u));
                *reinterpret_cast<float*>(DCUR + swz256(row, f*4u)) = v;
                *reinterpret_cast<__bf16*>(XB2 + swz128(60u + row, f*2u)) = (__bf16)v;
            }
            __syncthreads();
            // (b) u-merge M=4 -> U[0:16)
            gemm_x<1>(XB2, 60, 4, Ub, 0, wlf, nt, BL);
            __syncthreads();
            // (c) nl-merge -> hc_alt (stale-row overreads benign: they only
            //     contaminate out rows >= 4, never rows 0-3)
            v4f c = (v4f){0,0,0,0};
            #pragma unroll
            for (uint32_t kf = 0; kf < 12; ++kf){
                const char* src = (kf < 4) ? hl : ((kf < 8) ? (const char*)hc_cur
                                                            : (const char*)Ub);
                c = mfma16(ldH(src, kf & 3u), wnl[kf], c);
            }
            epi(hc_alt, 0, c, nt, BN);
            { char* tmp = hc_cur; hc_cur = hc_alt; hc_alt = tmp; }
            if (m == nm - 1) __syncthreads();
        }
    }

    // ---- head: z1 = relu(root@W1+b1) -> U; z2 -> HB; out = z2@W3+b3 ----
    {
        v8bf w1f[4], w2f[4];
        #pragma unroll
        for (int kf = 0; kf < 4; ++kf){
            w1f[kf] = ldW(W1g, kf*32, n0);
            w2f[kf] = ldW(W2g, kf*32, n0);
        }
        {
            v4f c = (v4f){0,0,0,0};
            #pragma unroll
            for (uint32_t kf = 0; kf < 4; ++kf) c = mfma16(ldH(hc_cur, kf), w1f[kf], c);
            epi(Ub, 0, c, nt, B1L);
        }
        __syncthreads();
        {
            v4f c = (v4f){0,0,0,0};
            #pragma unroll
            for (uint32_t kf = 0; kf < 4; ++kf) c = mfma16(ldH(Ub, kf), w2f[kf], c);
            epi(HB, 0, c, nt, B2L);
        }
        __syncthreads();
        if (t < 64){
            float w3a = W3g[t], w3b = W3g[t + 64], b3v = b3g[0];
            #pragma unroll
            for (int r = 0; r < BC; ++r){
                float za = (float)*reinterpret_cast<const __bf16*>(HB + swz256((uint32_t)r, (uint32_t)t*2u));
                float zb = (float)*reinterpret_cast<const __bf16*>(HB + swz256((uint32_t)r, (uint32_t)(t + 64)*2u));
                float v = za*w3a + zb*w3b;
                #pragma unroll
                for (int off = 32; off >= 1; off >>= 1) v += __shfl_xor(v, off, 64);
                if (t == 0) Yg[base + r] = v + b3v;
            }
        }
    }
}

extern "C" void kernel_launch(void* const* d_in, const int* in_sizes, int n_in,
                              void* d_out, int out_size, void* d_ws, size_t ws_size,
                              hipStream_t stream){
    const float* x     = (const float*)d_in[0];
    const float* Wleaf = (const float*)d_in[1];
    const float* bleaf = (const float*)d_in[2];
    const float* Wnl   = (const float*)d_in[3];
    const float* bnl   = (const float*)d_in[4];
    const float* W1    = (const float*)d_in[5];
    const float* b1    = (const float*)d_in[6];
    const float* W2    = (const float*)d_in[7];
    const float* b2    = (const float*)d_in[8];
    const float* W3    = (const float*)d_in[9];
    const float* b3    = (const float*)d_in[10];
    float* out = (float*)d_out;

    recnn_kernel<<<B_TOT/BC, NTHR, 0, stream>>>(x, Wleaf, bleaf, Wnl, bnl,
                                                W1, b1, W2, b2, W3, b3, out);
}

// Round 18
// 125.464 us; speedup vs baseline: 1.2867x; 1.2867x over previous
//
#include <hip/hip_runtime.h>
#include <hip/hip_bf16.h>
#include <stdint.h>

// RecNN: B=2048, L=256, F=64, H=128. One WG (512 thr, 8 waves) per 8 batch
// elems. Subtree-BFS(16 leaves) + DFS over 16 roots. Each wave owns ONE
// 16-col output tile (nt=wave, 56 weight VGPRs) at 2 waves/SIMD — the ONLY
// viable config (pinned by R2-R17):
//  * HW wave-slot cost ~= 2x arch VGPR (unified-file accum mirror): 2 blocks
//    per CU needs arch<=64 which spills (R15); wider N needs 112 weight regs
//    which spills at 128 (R2/3/5) and AGPR parking fails 3 ways (R6/7/12/13).
//  * 1 wave/SIMD (R9) is ds_read-latency-bound.
// This kernel = R11 verbatim (125.7us): bf16 mirror panels (single b128
// A-read per fragment), fused {nl_i, u_{i+1}} phases, HCUR double-buffered
// merges, f32 exact pairwise data sums. ~90% LDS-pipe utilization; the 2-way
// read collisions in SQ_LDS_BANK_CONFLICT are timing-free (m136; R8 vs R10
// bit-identical counter).

#define B_TOT 2048
#define LL    256
#define FF    64
#define HH    128
#define LF    (LL*FF)
#define BC    8
#define NTHR  512
#define NSUB  16

typedef __bf16 v8bf __attribute__((ext_vector_type(8)));
typedef float  v4f  __attribute__((ext_vector_type(4)));

// ---- LDS layout (bytes) ----
#define XB_OFF    0        // [128]x128B bf16 swz128: leaf x            16384
#define XB2_OFF   16384    // [128]x128B bf16 swz128: data1..4 + root   16384
#define DB_OFF    32768    // [64]x256B f32 swz256: data1 / data3       16384
#define DB2_OFF   49152    // [40]x256B: rows0-31 data2 f32 then U2 bf16;
                           //            rows32-39 data4 f32            10240
#define HA_OFF    59392    // [128]x256B bf16 swz256: h0 / h2           32768
#define HB_OFF    92160    // [64]x256B bf16: h1 / h3 / z2              16384
#define U_OFF     108544   // [64]x256B bf16: u1 / u3@0 / u4@16 / z1    16384
#define HCA_OFF   124928   // [16]x256B bf16: root h (buffer A)          4096
#define HCB_OFF   129024   // [16]x256B bf16: root h (buffer B)          4096
#define DCUR_OFF  133120   // [8]x256B f32: root data                    2048
#define HSTK_OFF  135168   // 4 x 2048 (8 real rows each)                8192
#define DSTK_OFF  143360   // 4 x 2048                                   8192
#define BIAS_OFF  151552   // 4 x 512B f32                               2048
#define LDS_BYTES 153600

__device__ __forceinline__ uint32_t swz256(uint32_t row, uint32_t b){
    return (row*256u + b) ^ ((row & 7u) << 4);
}
__device__ __forceinline__ uint32_t swz128(uint32_t row, uint32_t b){
    return (row*128u + b) ^ ((row & 7u) << 4);
}
__device__ __forceinline__ v4f mfma16(v8bf a, v8bf b, v4f c){
    return __builtin_amdgcn_mfma_f32_16x16x32_bf16(a, b, c, 0, 0, 0);
}
__device__ __forceinline__ uint32_t pk2(float a, float b){
    uint32_t lo = (uint32_t)__builtin_bit_cast(unsigned short, (__bf16)a);
    uint32_t hi = (uint32_t)__builtin_bit_cast(unsigned short, (__bf16)b);
    return lo | (hi << 16);
}
__device__ __forceinline__ uint2 pk4(v4f v){
    return make_uint2(pk2(v[0], v[1]), pk2(v[2], v[3]));
}

// B-fragment: lane holds col n0+(l&15), k = k0 + 8*(l>>4) + j. W row-major [K][128] f32.
__device__ __forceinline__ v8bf ldW(const float* __restrict__ W, int k0, int n0){
    uint32_t lane = threadIdx.x & 63u;
    int n = n0 + (int)(lane & 15u);
    int k = k0 + (int)((lane >> 4) << 3);
    v8bf r;
    #pragma unroll
    for (int j = 0; j < 8; ++j) r[j] = (__bf16)W[(k + j)*HH + n];
    return r;
}

// A-frag from bf16 64-col panel (swz128). rows >= realrows -> 0.
__device__ __forceinline__ v8bf ldX(const char* xb, uint32_t row0, uint32_t mt,
                                    uint32_t kf, uint32_t realrows){
    uint32_t lane = threadIdx.x & 63u;
    uint32_t rl = mt*16u + (lane & 15u);
    if (rl >= realrows){
        v8bf z;
        #pragma unroll
        for (int j = 0; j < 8; ++j) z[j] = (__bf16)0.0f;
        return z;
    }
    return *reinterpret_cast<const v8bf*>(xb + swz128(row0 + rl, kf*64u + ((lane>>4)<<4)));
}

// A-frag from 16-row bf16 buffer (swz256), row = lane&15 (merge/head GEMMs)
__device__ __forceinline__ v8bf ldH(const char* buf, uint32_t kf){
    uint32_t lane = threadIdx.x & 63u;
    return *reinterpret_cast<const v8bf*>(buf + swz256(lane & 15u,
                                          kf*64u + ((lane>>4)<<4)));
}

// A-frag for subtree nl GEMM (node-major): out tile mt -> nodes 2mt,2mt+1;
// children rows 32mt+16*(r>=8)+8*sec+(r&7); u row 16mt+r.
__device__ __forceinline__ v8bf ldA_nl(const char* hprev, const char* ub,
                                       uint32_t mt, uint32_t kf){
    uint32_t lane = threadIdx.x & 63u, r = lane & 15u;
    uint32_t kb = (kf & 3u)*64u + ((lane >> 4) << 4);
    uint32_t sec = kf >> 2;
    if (sec < 2u){
        uint32_t row = mt*32u + ((r >> 3) << 4) + sec*8u + (r & 7u);
        return *reinterpret_cast<const v8bf*>(hprev + swz256(row, kb));
    }
    return *reinterpret_cast<const v8bf*>(ub + swz256(mt*16u + r, kb));
}

// Epilogue: relu(acc+bias) -> bf16 swz256 LDS, rows row0+(l>>4)*4+r, col 16nt+(l&15)
__device__ __forceinline__ void epi(char* dst, uint32_t row0, v4f acc, int nt,
                                    const float* bias){
    uint32_t lane = threadIdx.x & 63u;
    uint32_t col = (uint32_t)nt*16u + (lane & 15u);
    float bv = bias[col];
    uint32_t r0 = row0 + ((lane >> 4) << 2);
    #pragma unroll
    for (int r = 0; r < 4; ++r){
        float v = fmaxf(acc[r] + bv, 0.f);
        *reinterpret_cast<__bf16*>(dst + swz256(r0 + r, col*2u)) = (__bf16)v;
    }
}

// data/leaf GEMM: relu(A @ Wleaf + b), A from bf16 panel, 1 nt per wave
template<int MTN>
__device__ __forceinline__ void gemm_x(const char* xb, uint32_t row0, uint32_t realrows,
                                       char* dst, uint32_t mtB, const v8bf (&wlf)[2],
                                       int nt, const float* bias){
    v4f acc[MTN];
    #pragma unroll
    for (int i = 0; i < MTN; ++i) acc[i] = (v4f){0,0,0,0};
    #pragma unroll
    for (uint32_t kf = 0; kf < 2; ++kf){
        v8bf a[MTN];
        #pragma unroll
        for (int i = 0; i < MTN; ++i) a[i] = ldX(xb, row0, mtB + i, kf, realrows);
        #pragma unroll
        for (int i = 0; i < MTN; ++i) acc[i] = mfma16(a[i], wlf[kf], acc[i]);
    }
    #pragma unroll
    for (int i = 0; i < MTN; ++i) epi(dst, (mtB + i)*16u, acc[i], nt, bias);
}

// nl GEMM: relu([h_even|h_odd|u] @ Wnl + b), node-major, 1 nt per wave
template<int MTN>
__device__ __forceinline__ void gemm_nl(const char* hprev, const char* ub, char* dst,
                                        uint32_t mtB, const v8bf (&wnl)[12],
                                        int nt, const float* bias){
    v4f acc[MTN];
    #pragma unroll
    for (int i = 0; i < MTN; ++i) acc[i] = (v4f){0,0,0,0};
    #pragma unroll
    for (uint32_t kf = 0; kf < 12; ++kf){
        v8bf a[MTN];
        #pragma unroll
        for (int i = 0; i < MTN; ++i) a[i] = ldA_nl(hprev, ub, mtB + i, kf);
        #pragma unroll
        for (int i = 0; i < MTN; ++i) acc[i] = mfma16(a[i], wnl[kf], acc[i]);
    }
    #pragma unroll
    for (int i = 0; i < MTN; ++i) epi(dst, (mtB + i)*16u, acc[i], nt, bias);
}

__global__ __launch_bounds__(NTHR)
__attribute__((amdgpu_waves_per_eu(2, 2)))
void recnn_kernel(const float* __restrict__ Xg,
                  const float* __restrict__ Wleaf, const float* __restrict__ bleaf,
                  const float* __restrict__ Wnl,   const float* __restrict__ bnl,
                  const float* __restrict__ W1g,   const float* __restrict__ b1g,
                  const float* __restrict__ W2g,   const float* __restrict__ b2g,
                  const float* __restrict__ W3g,   const float* __restrict__ b3g,
                  float* __restrict__ Yg)
{
    __shared__ __align__(16) char lds[LDS_BYTES];
    const int t    = threadIdx.x;
    const int wave = t >> 6;
    const int base = blockIdx.x * BC;

    char*  XB   = lds + XB_OFF;
    char*  XB2  = lds + XB2_OFF;
    char*  DB   = lds + DB_OFF;
    char*  DB2  = lds + DB2_OFF;
    char*  U2   = lds + DB2_OFF;           // rows 0-31, bf16 (data2-f32 dead by then)
    char*  HA   = lds + HA_OFF;
    char*  HB   = lds + HB_OFF;
    char*  Ub   = lds + U_OFF;
    char*  DCUR = lds + DCUR_OFF;
    char*  HSTK = lds + HSTK_OFF;
    char*  DSTK = lds + DSTK_OFF;
    float* BL   = (float*)(lds + BIAS_OFF);
    float* BN   = BL + 128;
    float* B1L  = BL + 256;
    float* B2L  = BL + 384;

    char* hc_cur = lds + HCA_OFF;
    char* hc_alt = lds + HCB_OFF;

    if (t < 128){
        BL[t]  = bleaf[t];
        BN[t]  = bnl[t];
        B1L[t] = b1g[t];
        B2L[t] = b2g[t];
    }

    // Persistent weights: wave owns output cols [16*wave, 16*wave+16) — 56 VGPRs
    const int nt = wave;
    const int n0 = wave << 4;
    v8bf wlf[2], wnl[12];
    #pragma unroll
    for (int kf = 0; kf < 2; ++kf)  wlf[kf] = ldW(Wleaf, kf*32, n0);
    #pragma unroll
    for (int kf = 0; kf < 12; ++kf) wnl[kf] = ldW(Wnl, kf*32, n0);

    // fused pairwise sum: srcF(swz256,node-major) -> dstF f32 + XB2 bf16 mirror
    auto sum_level = [&](char* dstF, uint32_t dRow0, uint32_t xRow0,
                         const char* srcF, uint32_t sRow0, int outrows){
        int total = outrows * 16;
        for (int idx = t; idx < total; idx += NTHR){
            uint32_t row = (uint32_t)(idx >> 4), q = (uint32_t)(idx & 15);
            uint32_t n = row >> 3, b = row & 7u;
            v4f a = *reinterpret_cast<const v4f*>(srcF + swz256(sRow0 + n*16u + b,      q*16u));
            v4f c = *reinterpret_cast<const v4f*>(srcF + swz256(sRow0 + n*16u + 8u + b, q*16u));
            v4f sv = a + c;
            *reinterpret_cast<v4f*>(dstF + swz256(dRow0 + row, q*16u)) = sv;
            *reinterpret_cast<uint2*>(XB2 + swz128(xRow0 + row, q*8u)) = pk4(sv);
        }
    };

    int sp = 0;
    for (int s = 0; s < NSUB; ++s){
        // push previous root (8 real rows = 2048B each)
        if (s > 0){
            ((uint32_t*)(HSTK + sp*2048))[t] = ((const uint32_t*)hc_cur)[t];
            ((uint32_t*)(DSTK + sp*2048))[t] = ((const uint32_t*)DCUR)[t];
            ++sp;
        }
        // stage: x -> XB bf16; data1 -> DB f32 + XB2[0:64) bf16
        #pragma unroll
        for (int k = 0; k < 2; ++k){
            int idx = t + k*NTHR;                  // 0..1023
            uint32_t rp = (uint32_t)(idx >> 4), q = (uint32_t)(idx & 15);
            uint32_t n = rp >> 3, b = rp & 7u;
            const float* gp = Xg + (size_t)(base + b)*LF + (size_t)(s*16 + 2*n)*FF + q*4;
            v4f xA = *reinterpret_cast<const v4f*>(gp);
            v4f xC = *reinterpret_cast<const v4f*>(gp + FF);
            uint32_t rowA = n*16u + b;
            *reinterpret_cast<uint2*>(XB + swz128(rowA,      q*8u)) = pk4(xA);
            *reinterpret_cast<uint2*>(XB + swz128(rowA + 8u, q*8u)) = pk4(xC);
            v4f sv = xA + xC;
            *reinterpret_cast<v4f*>(DB + swz256(rp, q*16u)) = sv;
            *reinterpret_cast<uint2*>(XB2 + swz128(rp, q*8u)) = pk4(sv);
        }
        __syncthreads();

        // F1: leaf M=128 -> HA ; data2 = sum(data1) -> DB2[0:32)f32 + XB2[64:96)
        gemm_x<4>(XB, 0, 128, HA, 0, wlf, nt, BL);
        gemm_x<4>(XB, 0, 128, HA, 4, wlf, nt, BL);
        sum_level(DB2, 0, 64, DB, 0, 32);
        __syncthreads();

        // F2: u1 M=64 -> U ; data3 = sum(data2 f32) -> DB[0:16) + XB2[96:112)
        gemm_x<4>(XB2, 0, 64, Ub, 0, wlf, nt, BL);
        sum_level(DB, 0, 96, DB2, 0, 16);
        __syncthreads();

        // F3: nl1 M=64 -> HB ; u2 M=32 -> U2 (over dead data2 f32) ;
        //     data4 = sum(data3) -> DB2[32:40) + XB2[112:120)
        gemm_nl<4>(HA, Ub, HB, 0, wnl, nt, BN);
        gemm_x<2>(XB2, 64, 32, U2, 0, wlf, nt, BL);
        sum_level(DB2, 32, 112, DB, 0, 8);
        __syncthreads();

        // F4: nl2 M=32 -> HA[0:32) ; u3 M=16 -> U[0:16)
        gemm_nl<2>(HB, U2, HA, 0, wnl, nt, BN);
        gemm_x<1>(XB2, 96, 16, Ub, 0, wlf, nt, BL);
        __syncthreads();

        // F5: nl3 M=16 -> HB[0:16) ; u4 M=8 -> U[16:32)
        gemm_nl<1>(HA, Ub, HB, 0, wnl, nt, BN);
        gemm_x<1>(XB2, 112, 8, Ub + 16*256, 0, wlf, nt, BL);
        __syncthreads();

        // F6: nl4 -> hc_cur ; DCUR <- data4 f32
        gemm_nl<1>(HB, Ub + 16*256, hc_cur, 0, wnl, nt, BN);
        {
            uint32_t row = (uint32_t)(t >> 6), f = (uint32_t)(t & 63);
            *reinterpret_cast<float*>(DCUR + swz256(row, f*4u)) =
                *reinterpret_cast<const float*>(DB2 + swz256(32u + row, f*4u));
        }
        __syncthreads();

        // DFS merges among subtree roots (M=8 padded to 16), HCUR double-buffered
        int nm = __builtin_ctz(s + 1);
        for (int m = 0; m < nm; ++m){
            --sp;
            const char* hl = HSTK + sp*2048;
            {   // (a) root data sum + bf16 mirror -> XB2[120:128)
                uint32_t row = (uint32_t)(t >> 6), f = (uint32_t)(t & 63);
                float v = *reinterpret_cast<const float*>(DCUR + swz256(row, f*4u))
                        + *reinterpret_cast<const float*>(DSTK + sp*2048 + swz256(row, f*4u));
                *reinterpret_cast<float*>(DCUR + swz256(row, f*4u)) = v;
                *reinterpret_cast<__bf16*>(XB2 + swz128(120u + row, f*2u)) = (__bf16)v;
            }
            __syncthreads();
            // (b) u-merge M=8 -> U[0:16)
            gemm_x<1>(XB2, 120, 8, Ub, 0, wlf, nt, BL);
            __syncthreads();
            // (c) nl-merge -> hc_alt (no in-place hazard; no barrier except last)
            v4f c = (v4f){0,0,0,0};
            #pragma unroll
            for (uint32_t kf = 0; kf < 12; ++kf){
                const char* src = (kf < 4) ? hl : ((kf < 8) ? (const char*)hc_cur
                                                            : (const char*)Ub);
                c = mfma16(ldH(src, kf & 3u), wnl[kf], c);
            }
            epi(hc_alt, 0, c, nt, BN);
            { char* tmp = hc_cur; hc_cur = hc_alt; hc_alt = tmp; }
            if (m == nm - 1) __syncthreads();
        }
    }

    // ---- head: z1 = relu(root@W1+b1) -> U; z2 -> HB; out = z2@W3+b3 ----
    {
        v8bf w1f[4], w2f[4];
        #pragma unroll
        for (int kf = 0; kf < 4; ++kf){
            w1f[kf] = ldW(W1g, kf*32, n0);
            w2f[kf] = ldW(W2g, kf*32, n0);
        }
        {
            v4f c = (v4f){0,0,0,0};
            #pragma unroll
            for (uint32_t kf = 0; kf < 4; ++kf) c = mfma16(ldH(hc_cur, kf), w1f[kf], c);
            epi(Ub, 0, c, nt, B1L);
        }
        __syncthreads();
        {
            v4f c = (v4f){0,0,0,0};
            #pragma unroll
            for (uint32_t kf = 0; kf < 4; ++kf) c = mfma16(ldH(Ub, kf), w2f[kf], c);
            epi(HB, 0, c, nt, B2L);
        }
        __syncthreads();
        if (t < 64){
            float w3a = W3g[t], w3b = W3g[t + 64], b3v = b3g[0];
            #pragma unroll
            for (int r = 0; r < 8; ++r){
                float za = (float)*reinterpret_cast<const __bf16*>(HB + swz256((uint32_t)r, (uint32_t)t*2u));
                float zb = (float)*reinterpret_cast<const __bf16*>(HB + swz256((uint32_t)r, (uint32_t)(t + 64)*2u));
                float v = za*w3a + zb*w3b;
                #pragma unroll
                for (int off = 32; off >= 1; off >>= 1) v += __shfl_xor(v, off, 64);
                if (t == 0) Yg[base + r] = v + b3v;
            }
        }
    }
}

extern "C" void kernel_launch(void* const* d_in, const int* in_sizes, int n_in,
                              void* d_out, int out_size, void* d_ws, size_t ws_size,
                              hipStream_t stream){
    const float* x     = (const float*)d_in[0];
    const float* Wleaf = (const float*)d_in[1];
    const float* bleaf = (const float*)d_in[2];
    const float* Wnl   = (const float*)d_in[3];
    const float* bnl   = (const float*)d_in[4];
    const float* W1    = (const float*)d_in[5];
    const float* b1    = (const float*)d_in[6];
    const float* W2    = (const float*)d_in[7];
    const float* b2    = (const float*)d_in[8];
    const float* W3    = (const float*)d_in[9];
    const float* b3    = (const float*)d_in[10];
    float* out = (float*)d_out;

    recnn_kernel<<<B_TOT/BC, NTHR, 0, stream>>>(x, Wleaf, bleaf, Wnl, bnl,
                                                W1, b1, W2, b2, W3, b3, out);
}